// Round 13
// baseline (123.913 us; speedup 1.0000x reference)
//
#include <hip/hip_runtime.h>
#include <cstdint>

// ---------------------------------------------------------------------------
// GRUCell w/ BatchNorm on input projection.  B=4096, I=H=1024, 3H=3072.
// Reference:  c = tanh(c_bn + (r * hx) @ c_h)  (Python left-assoc * then @).
// fp16 scheme (mfma_f32_16x16x32_f16, fp32 accum):
//   MEGA (1536 blocks, 32KB LDS):
//     blocks 0..1023 : 128x128 1-pass over [g(3072c) | gh_u(1024c)]
//       g-blocks stage A DIRECTLY from f32 input (fused convert, round-13)
//     blocks 1024..1535: 128x64 2-pass (B hi+lo) over gh_r(1024c)
//     bx-fast order within XCD (round-11: FETCH 99->79MB)
//   bn_final -> scale/shift;  rx = sigmoid(BN(g_r)+gh_r)*hx  (fp16)
//   GEMM3: ch = rx @ wh_c, 64x64 BK=128, 1024 blocks; epilogue u+hy.
// Lessons: blocks/CU >= 4 beats tile density (r5/r11); BK depth is the safe
// density lever (r12); bx-fast = L2 reuse (r11).
// ---------------------------------------------------------------------------

typedef float    f4    __attribute__((ext_vector_type(4)));
typedef _Float16 half4 __attribute__((ext_vector_type(4)));
typedef _Float16 half8 __attribute__((ext_vector_type(8)));
typedef float    f32x4 __attribute__((ext_vector_type(4)));

__device__ __forceinline__ float sigm(float x) { return 1.f / (1.f + __expf(-x)); }
__device__ __forceinline__ float tanh_sat(float t) {
  return 1.f - 2.f / (__expf(2.f * t) + 1.f);   // saturates correctly for big t
}

// async global->LDS DMA, 16B/lane: LDS dst = wave-uniform base + lane*16
__device__ __forceinline__ void gload16(const _Float16* g, _Float16* l) {
  __builtin_amdgcn_global_load_lds(
      (const __attribute__((address_space(1))) void*)g,
      (__attribute__((address_space(3))) void*)l, 16, 0, 0);
}

// --------------------------- prep (one dispatch) ----------------------------
// bid < 4096: f32->fp16 convert of hx (x4 vectorized; 1048576 float4s).
// bid >= 4096: 32x32 transpose tiles; z=0 -> wi->WiT; z=1 -> wh->WhTh(+lo r).

__global__ void prep_all(const float* __restrict__ hx,
                         const float* __restrict__ wi, const float* __restrict__ wh,
                         _Float16* __restrict__ Hf16, _Float16* __restrict__ WiT,
                         _Float16* __restrict__ WhTh, _Float16* __restrict__ WhTl) {
  __shared__ float sh[32][33];
  int bid = blockIdx.x;
  if (bid < 4096) {                     // 4096*256 = 1048576 float4s exactly
    int i = bid * 256 + threadIdx.x;
    f4 v = ((const f4*)hx)[i];
    half4 h;
#pragma unroll
    for (int j = 0; j < 4; ++j) h[j] = (_Float16)v[j];
    ((half4*)Hf16)[i] = h;
    return;
  }
  int b2 = bid - 4096;                  // 0..6143: [z][ky 0..31][nx 0..95]
  int z = b2 / 3072; b2 %= 3072;
  int nx = b2 % 96, ky = b2 / 96;
  const float* W = z ? wh : wi;
  int n0 = nx * 32, k0 = ky * 32;
  int tx = threadIdx.x & 31, ty = threadIdx.x >> 5;  // ty 0..7
#pragma unroll
  for (int i = 0; i < 4; ++i) {
    int k = ty + i * 8;
    sh[k][tx] = W[(size_t)(k0 + k) * 3072 + n0 + tx];
  }
  __syncthreads();
  const bool wlo = z && n0 >= 1024 && n0 < 2048;     // r-cols need lo part
#pragma unroll
  for (int i = 0; i < 4; ++i) {
    int nn = ty + i * 8;
    float v = sh[tx][nn];                      // = W[k0+tx][n0+nn]
    size_t o = (size_t)(n0 + nn) * 1024 + k0 + tx;
    _Float16 h = (_Float16)v;
    if (!z) {
      WiT[o] = h;
    } else {
      WhTh[o] = h;
      if (wlo) WhTl[o] = (_Float16)(v - (float)h);
    }
  }
}

// ------------------------------- GEMM core ----------------------------------
// BMt x BNt tile, BKt in {64,128}, 4 waves (2x2).  LDS [rows][BKt/8 slots of
// 8 fp16]; LDS slot S of row r holds k-group S^(r&7).
//   AF32=false: global_load_lds with inverse-swizzled global source (dest
//               linear).  AF32=true: A is f32; reg-load + cvt + ds_write to
//               the swizzled slot (same involution -> identical layout).
// Read side: slot kg^(r&7) yields k-group kg.  B gload issued FIRST so the
// DMA is in flight during the AF32 register round-trip.
// K-loop: barrier; stage(kt); barrier; compute(kt).

template <bool AF32, bool LO, int BMt, int BNt, int BKt>
__device__ __forceinline__ void kloop(
    const void* __restrict__ Av, const _Float16* __restrict__ Bh,
    const _Float16* __restrict__ Bl, _Float16* lds, int tid,
    f32x4 (&acc)[BMt / 32][BNt / 32]) {
  constexpr int TA = BMt * BKt, TB = BNt * BKt;
  constexpr int MF = BMt / 32, WC = BNt / 32;
  constexpr int NT = 1024 / BKt;
  constexpr int RPC = 512 / BKt;          // rows per 1KB staging chunk
  constexpr int SLOTS = BKt / 8;          // 16B k-groups per row
  constexpr int AW = TA / 512 / 4;        // A chunks per wave
  constexpr int BW = TB / 512 / 4;        // B chunks per wave
  const int lane = tid & 63, wid = tid >> 6;
  const int srow  = lane / SLOTS;         // row within chunk
  const int sslot = lane % SLOTS;
  const int wrow = (wid >> 1) * (BMt / 2);
  const int wcol = (wid & 1) * (BNt / 2);

  for (int kt = 0; kt < NT; ++kt) {
    const int k0 = kt * BKt;
    __syncthreads();                  // all waves done reading prev tile
    // ---- B first (fire-and-forget DMA)
#pragma unroll
    for (int i = 0; i < BW; ++i) {
      int c = wid * BW + i;
      int rg = c * RPC + srow;
      size_t go = (size_t)rg * 1024 + k0 + ((sslot ^ (rg & 7)) << 3);
      gload16(Bh + go, lds + TA + c * 512);
      if constexpr (LO) gload16(Bl + go, lds + TA + TB + c * 512);
    }
    // ---- A
#pragma unroll
    for (int i = 0; i < AW; ++i) {
      int c = wid * AW + i;
      int rg = c * RPC + srow;
      if constexpr (AF32) {
        const float* src = (const float*)Av + (size_t)rg * 1024 + k0 + sslot * 8;
        f4 v0 = *(const f4*)src;
        f4 v1 = *(const f4*)(src + 4);
        half8 hv;
#pragma unroll
        for (int j = 0; j < 4; ++j) { hv[j] = (_Float16)v0[j]; hv[4 + j] = (_Float16)v1[j]; }
        *(half8*)(lds + c * 512 + srow * BKt + ((sslot ^ (rg & 7)) << 3)) = hv;
      } else {
        gload16((const _Float16*)Av + (size_t)rg * 1024 + k0 +
                    ((sslot ^ (rg & 7)) << 3),
                lds + c * 512);
      }
    }
    __syncthreads();                  // drains vmcnt(0)+lgkmcnt -> LDS valid

#pragma unroll
    for (int h = 0; h < BKt / 32; ++h) {
      half8 a[MF], bhv[WC], blv[WC];
      const int kg = h * 4 + (lane >> 4);
#pragma unroll
      for (int m = 0; m < MF; ++m) {
        int r = wrow + m * 16 + (lane & 15);
        a[m] = *(const half8*)(lds + r * BKt + ((kg ^ (r & 7)) << 3));
      }
#pragma unroll
      for (int n = 0; n < WC; ++n) {
        int r = wcol + n * 16 + (lane & 15);
        int off = TA + r * BKt + ((kg ^ (r & 7)) << 3);
        bhv[n] = *(const half8*)(lds + off);
        if constexpr (LO) blv[n] = *(const half8*)(lds + TB + off);
      }
#pragma unroll
      for (int m = 0; m < MF; ++m)
#pragma unroll
        for (int n = 0; n < WC; ++n) {
          acc[m][n] = __builtin_amdgcn_mfma_f32_16x16x32_f16(
              a[m], bhv[n], acc[m][n], 0, 0, 0);
          if constexpr (LO)
            acc[m][n] = __builtin_amdgcn_mfma_f32_16x16x32_f16(
                a[m], blv[n], acc[m][n], 0, 0, 0);
        }
    }
  }
}

// ---- MEGA: 1536 blocks.  0..1023: 128x128 1-pass over [g | gh_u] (4096c);
//      g-blocks read A from f32 input (fused convert).
//      1024..1535: 128x64 2-pass over gh_r (1024c).  bx-fast within XCD.
__global__ __launch_bounds__(256, 4) void gemm_mega(
    const float* __restrict__ input32, const _Float16* __restrict__ Hf16,
    const _Float16* __restrict__ WiT, const _Float16* __restrict__ WhTh,
    const _Float16* __restrict__ WhTl, _Float16* __restrict__ g16,
    _Float16* __restrict__ ghbuf, float* __restrict__ psum,
    float* __restrict__ psq) {
  __shared__ _Float16 lds[16384];                    // 32 KiB both phases

  const int tid  = threadIdx.x;
  const int lane = tid & 63;
  const int wid  = tid >> 6;
  const int bid  = blockIdx.x;

  if (bid < 1024) {
    // ---- phase 1: 128x128, 1-pass.  XCD owns 4 col-panels; bx fast.
    int xcd   = bid & 7;
    int local = bid >> 3;                            // 0..127
    int bx = xcd * 4 + (local & 3);                  // 0..31
    int by = local >> 2;                             // 0..31
    const int brow = by * 128;
    const int bcol = bx * 128;                       // 0..4095
    const bool is_g = bcol < 3072;
    const int wrow = (wid >> 1) * 64;
    const int wcol = (wid & 1) * 64;

    f32x4 acc[4][4];
#pragma unroll
    for (int i = 0; i < 4; ++i)
#pragma unroll
      for (int j = 0; j < 4; ++j) acc[i][j] = f32x4{0.f, 0.f, 0.f, 0.f};

    if (is_g) {
      kloop<true, false, 128, 128, 64>(input32 + (size_t)brow * 1024,
                                       WiT + (size_t)bcol * 1024, nullptr,
                                       lds, tid, acc);
    } else {
      kloop<false, false, 128, 128, 64>(Hf16 + (size_t)brow * 1024,
                                        WhTh + (size_t)(bcol - 3072) * 1024,
                                        nullptr, lds, tid, acc);
    }

    // D(row,col): col = lane&15, row = (lane>>4)*4 + j
    if (is_g) {                       // g (fp16) + BN column partial sums
      float s[4] = {0.f, 0.f, 0.f, 0.f}, q[4] = {0.f, 0.f, 0.f, 0.f};
#pragma unroll
      for (int m = 0; m < 4; ++m) {
        int row = brow + wrow + m * 16 + (lane >> 4) * 4;
#pragma unroll
        for (int n = 0; n < 4; ++n) {
          int gcol = bcol + wcol + n * 16 + (lane & 15);
#pragma unroll
          for (int j = 0; j < 4; ++j) {
            float v = acc[m][n][j];
            g16[(size_t)(row + j) * 3072 + gcol] = (_Float16)v;
            s[n] += v;
            q[n] += v * v;
          }
        }
      }
#pragma unroll
      for (int n = 0; n < 4; ++n) {
        float sv = s[n], qv = q[n];
        sv += __shfl_xor(sv, 16); sv += __shfl_xor(sv, 32);
        qv += __shfl_xor(qv, 16); qv += __shfl_xor(qv, 32);
        if (lane < 16) {
          int prow = by * 2 + (wid >> 1);            // 64 partial rows
          int pcol = bcol + wcol + n * 16 + lane;
          psum[(size_t)prow * 3072 + pcol] = sv;
          psq [(size_t)prow * 3072 + pcol] = qv;
        }
      }
    } else {                          // raw gh_u (fp16), ghbuf stride 2048
      int gh0 = bcol - 3072;
#pragma unroll
      for (int m = 0; m < 4; ++m) {
        int row = brow + wrow + m * 16 + (lane >> 4) * 4;
#pragma unroll
        for (int n = 0; n < 4; ++n) {
          int gcol = gh0 + wcol + n * 16 + (lane & 15);
#pragma unroll
          for (int j = 0; j < 4; ++j)
            ghbuf[(size_t)(row + j) * 2048 + gcol] = (_Float16)acc[m][n][j];
        }
      }
    }
  } else {
    // ---- phase 2: 128x64, 2-pass (B hi+lo) over gh_r.  XCD: 2 panels, bx fast.
    int b2    = bid - 1024;                          // 0..511
    int xcd   = b2 & 7;
    int local = b2 >> 3;                             // 0..63
    int bx = xcd * 2 + (local & 1);                  // 0..15
    int by = local >> 1;                             // 0..31
    const int brow = by * 128;
    const int bcol = bx * 64;                        // 0..1023 within r
    const int wrow = (wid >> 1) * 64;
    const int wcol = (wid & 1) * 32;

    f32x4 acc[4][2];
#pragma unroll
    for (int i = 0; i < 4; ++i)
#pragma unroll
      for (int j = 0; j < 2; ++j) acc[i][j] = f32x4{0.f, 0.f, 0.f, 0.f};

    kloop<false, true, 128, 64, 64>(Hf16 + (size_t)brow * 1024,
                                    WhTh + (size_t)(1024 + bcol) * 1024,
                                    WhTl + (size_t)(1024 + bcol) * 1024,
                                    lds, tid, acc);

#pragma unroll
    for (int m = 0; m < 4; ++m) {
      int row = brow + wrow + m * 16 + (lane >> 4) * 4;
#pragma unroll
      for (int n = 0; n < 2; ++n) {
        int gcol = 1024 + bcol + wcol + n * 16 + (lane & 15);   // gh_r cols
#pragma unroll
        for (int j = 0; j < 4; ++j)
          ghbuf[(size_t)(row + j) * 2048 + gcol] = (_Float16)acc[m][n][j];
      }
    }
  }
}

// ---- GEMM3: ch = rx @ wh_c (64x64 tiles, BK=128, 1024 blocks);
//      epilogue computes u (from raw gh_u) and hy.
__global__ __launch_bounds__(256, 4) void gemm_last(
    const _Float16* __restrict__ RXf16, const _Float16* __restrict__ Bc,
    const _Float16* __restrict__ g16, const _Float16* __restrict__ ghbuf,
    const _Float16* __restrict__ Hf16, const float* __restrict__ scale,
    const float* __restrict__ shift, float* __restrict__ out) {
  __shared__ _Float16 lds[64 * 128 + 64 * 128];      // 32 KiB

  const int tid  = threadIdx.x;
  const int lane = tid & 63;
  const int wid  = tid >> 6;

  int bid   = blockIdx.x;                            // 0..1023
  int xcd   = bid & 7;
  int local = bid >> 3;                              // 0..127
  int bx = xcd * 2 + (local & 1);                    // 0..15
  int by = local >> 1;                               // 0..63

  const int brow = by * 64;
  const int bcol = bx * 64;                          // 0..1023
  const int wrow = (wid >> 1) * 32;
  const int wcol = (wid & 1) * 32;

  f32x4 acc[2][2];
#pragma unroll
  for (int i = 0; i < 2; ++i)
#pragma unroll
    for (int j = 0; j < 2; ++j) acc[i][j] = f32x4{0.f, 0.f, 0.f, 0.f};

  kloop<false, false, 64, 64, 128>(RXf16 + (size_t)brow * 1024,
                                   Bc + (size_t)bcol * 1024, nullptr,
                                   lds, tid, acc);

#pragma unroll
  for (int m = 0; m < 2; ++m) {
    int row0 = brow + wrow + m * 16 + (lane >> 4) * 4;
#pragma unroll
    for (int n = 0; n < 2; ++n) {
      int lcol = bcol + wcol + n * 16 + (lane & 15);
      float sc_u = scale[lcol],        sf_u = shift[lcol];
      float sc_c = scale[2048 + lcol], sf_c = shift[2048 + lcol];
#pragma unroll
      for (int j = 0; j < 4; ++j) {
        int row = row0 + j;
        float gu = (float)g16[(size_t)row * 3072 + lcol];
        float hu = (float)ghbuf[(size_t)row * 2048 + lcol];
        float u  = sigm(gu * sc_u + sf_u + hu);
        float gc = (float)g16[(size_t)row * 3072 + 2048 + lcol];
        float c  = tanh_sat(gc * sc_c + sf_c + acc[m][n][j]);
        float x  = (float)Hf16[(size_t)row * 1024 + lcol];
        out[(size_t)row * 1024 + lcol] = x + u * (c - x);
      }
    }
  }
}

// --------------------------- BN final ---------------------------------------

__global__ void bn_final(const float* __restrict__ psum, const float* __restrict__ psq,
                         const float* __restrict__ gamma, const float* __restrict__ beta,
                         const float* __restrict__ bias, float* __restrict__ scale,
                         float* __restrict__ shift, int nparts, int Ncols, float invM) {
  int col = blockIdx.x * blockDim.x + threadIdx.x;
  if (col >= Ncols) return;
  float s = 0.f, q = 0.f;
  for (int i = 0; i < nparts; ++i) {
    s += psum[(size_t)i * Ncols + col];
    q += psq [(size_t)i * Ncols + col];
  }
  float m   = s * invM;
  float var = q * invM - m * m;
  float r   = rsqrtf(var + 1e-5f);
  float sc  = r * gamma[col];
  scale[col] = sc;
  shift[col] = beta[col] + bias[col] - m * sc;
}

// --------------------- rx = sigmoid(BN(g_r)+gh_r) * hx ----------------------

__global__ void rx_split(const _Float16* __restrict__ g16,
                         const _Float16* __restrict__ ghbuf,
                         const _Float16* __restrict__ Hf16,
                         const float* __restrict__ scale,
                         const float* __restrict__ shift,
                         _Float16* __restrict__ rx) {
  int idx = blockIdx.x * blockDim.x + threadIdx.x;   // 4096*256
  int row = idx >> 8;
  int cv  = idx & 255;
  half4 gr = ((const half4*)g16)[(size_t)row * 768 + 256 + cv];   // g cols 1024+
  half4 hr = ((const half4*)ghbuf)[(size_t)row * 512 + 256 + cv]; // gh cols 1024+
  half4 xv = ((const half4*)Hf16)[(size_t)row * 256 + cv];
  int col = 1024 + cv * 4;
  f4 sr = *(const f4*)&scale[col];
  f4 fr = *(const f4*)&shift[col];
  half4 o;
#pragma unroll
  for (int j = 0; j < 4; ++j) {
    float r = sigm((float)gr[j] * sr[j] + fr[j] + (float)hr[j]);
    o[j] = (_Float16)(r * (float)xv[j]);
  }
  ((half4*)rx)[(size_t)row * 256 + cv] = o;
}

// ------------------------------ launch ---------------------------------------

extern "C" void kernel_launch(void* const* d_in, const int* in_sizes, int n_in,
                              void* d_out, int out_size, void* d_ws, size_t ws_size,
                              hipStream_t stream) {
  const float* input = (const float*)d_in[0];   // 4096x1024
  const float* hx    = (const float*)d_in[1];   // 4096x1024
  const float* wi    = (const float*)d_in[2];   // 1024x3072
  const float* wh    = (const float*)d_in[3];   // 1024x3072
  const float* bias  = (const float*)d_in[4];   // 3072
  const float* gamma = (const float*)d_in[5];   // 3072
  const float* beta  = (const float*)d_in[6];   // 3072
  float* out = (float*)d_out;

  const int B = 4096, N3 = 3072;

  char* ws = (char*)d_ws;
  _Float16* g16   = (_Float16*)(ws);               // 24 MiB [4096][3072]
  _Float16* ghbuf = (_Float16*)(ws + 25165824);    // 16 MiB [4096][2048] raw
  _Float16* Hf16  = (_Float16*)(ws + 41943040);    // 8 MiB
  _Float16* RXf16 = (_Float16*)(ws + 50331648);    // 8 MiB
  _Float16* WiT   = (_Float16*)(ws + 58720256);    // 6 MiB
  _Float16* WhTh  = (_Float16*)(ws + 65011712);    // 6 MiB
  _Float16* WhTl  = (_Float16*)(ws + 71303168);    // 6 MiB (r-cols only)
  float*    psum  = (float*)   (ws + 77594624);    // 768 KiB [64][3072]
  float*    psq   = (float*)   (ws + 78381056);    // 768 KiB
  float*    scale = (float*)   (ws + 79167488);    // 12 KiB
  float*    shift = (float*)   (ws + 79179776);    // 12 KiB

  // ---- prep: hx convert + transposes, one dispatch
  prep_all<<<4096 + 6144, 256, 0, stream>>>(hx, wi, wh,
                                            Hf16, WiT, WhTh, WhTl);

  // ---- MEGA GEMM: [g | gh_u] 128x128 1-pass (g: fused f32-A convert)
  //                 + gh_r 128x64 2-pass
  gemm_mega<<<1536, 256, 0, stream>>>(
      input, Hf16, WiT, WhTh, WhTl, g16, ghbuf, psum, psq);

  // ---- BN fold
  bn_final<<<12, 256, 0, stream>>>(psum, psq, gamma, beta, bias,
                                   scale, shift, 64, N3, 1.f / (float)B);

  // ---- rx = sigmoid(BN(g_r) + gh_r) * hx
  rx_split<<<4096, 256, 0, stream>>>(g16, ghbuf, Hf16, scale, shift, RXf16);

  // ---- GEMM3 + fused u/c/hy epilogue (64x64, BK=128, 1024 blocks)
  gemm_last<<<1024, 256, 0, stream>>>(
      RXf16, WhTh + (size_t)2048 * 1024, g16, ghbuf, Hf16, scale, shift, out);
}

// Round 14
// 118.020 us; speedup vs baseline: 1.0499x; 1.0499x over previous
//
#include <hip/hip_runtime.h>
#include <cstdint>

// ---------------------------------------------------------------------------
// GRUCell w/ BatchNorm on input projection.  B=4096, I=H=1024, 3H=3072.
// Reference:  c = tanh(c_bn + (r * hx) @ c_h)  (Python left-assoc * then @).
// fp16 scheme (mfma_f32_16x16x32_f16, fp32 accum):
//   MEGA (one dispatch, 1536 blocks, 32KB LDS both phases):
//     blocks 0..1023 : 128x128 1-pass over [g(3072c) | gh_u(1024c)]
//     blocks 1024..1535: 128x64 2-pass (B hi+lo) over gh_r(1024c)
//     bx-fast order within XCD (round-11: FETCH 99->79MB)
//   bn_final -> scale/shift;  rx = sigmoid(BN(g_r)+gh_r)*hx  (fp16)
//   GEMM3: ch = rx @ wh_c, 64x64 tiles BK=128, 1024 blocks; epilogue u+hy.
// Lessons: blocks/CU >= 4 beats tile density (r5/r11); BK depth is the safe
// density lever (r12); bx-fast = L2 reuse (r11); NO reg round-trip in mega
// staging -- gload_lds only (r6, r13 both confirmed).
// This round: revert r13's fused-convert regression to the r12 best config.
// ---------------------------------------------------------------------------

typedef float    f4    __attribute__((ext_vector_type(4)));
typedef _Float16 half4 __attribute__((ext_vector_type(4)));
typedef _Float16 half8 __attribute__((ext_vector_type(8)));
typedef float    f32x4 __attribute__((ext_vector_type(4)));

__device__ __forceinline__ float sigm(float x) { return 1.f / (1.f + __expf(-x)); }
__device__ __forceinline__ float tanh_sat(float t) {
  return 1.f - 2.f / (__expf(2.f * t) + 1.f);   // saturates correctly for big t
}

// async global->LDS DMA, 16B/lane: LDS dst = wave-uniform base + lane*16
__device__ __forceinline__ void gload16(const _Float16* g, _Float16* l) {
  __builtin_amdgcn_global_load_lds(
      (const __attribute__((address_space(1))) void*)g,
      (__attribute__((address_space(3))) void*)l, 16, 0, 0);
}

// --------------------------- prep (one dispatch) ----------------------------
// bid < 8192: f32->fp16 convert of input+hx (x4 vectorized; 2*1048576 float4s).
// bid >= 8192: 32x32 transpose tiles; z=0 -> wi->WiT; z=1 -> wh->WhTh(+lo r).

__global__ void prep_all(const float* __restrict__ input, const float* __restrict__ hx,
                         const float* __restrict__ wi, const float* __restrict__ wh,
                         _Float16* __restrict__ Xf16, _Float16* __restrict__ Hf16,
                         _Float16* __restrict__ WiT, _Float16* __restrict__ WhTh,
                         _Float16* __restrict__ WhTl) {
  constexpr int N4 = 4096 * 1024 / 4;   // float4s per input array = 1048576
  __shared__ float sh[32][33];
  int bid = blockIdx.x;
  if (bid < 8192) {                     // 8192*256 = 2*N4 threads exactly
    int i = bid * 256 + threadIdx.x;
    const float* s;
    _Float16* d;
    if (i < N4) { s = input; d = Xf16; }
    else        { s = hx;    d = Hf16; i -= N4; }
    f4 v = ((const f4*)s)[i];
    half4 h;
#pragma unroll
    for (int j = 0; j < 4; ++j) h[j] = (_Float16)v[j];
    ((half4*)d)[i] = h;
    return;
  }
  int b2 = bid - 8192;                  // 0..6143: [z][ky 0..31][nx 0..95]
  int z = b2 / 3072; b2 %= 3072;
  int nx = b2 % 96, ky = b2 / 96;
  const float* W = z ? wh : wi;
  int n0 = nx * 32, k0 = ky * 32;
  int tx = threadIdx.x & 31, ty = threadIdx.x >> 5;  // ty 0..7
#pragma unroll
  for (int i = 0; i < 4; ++i) {
    int k = ty + i * 8;
    sh[k][tx] = W[(size_t)(k0 + k) * 3072 + n0 + tx];
  }
  __syncthreads();
  const bool wlo = z && n0 >= 1024 && n0 < 2048;     // r-cols need lo part
#pragma unroll
  for (int i = 0; i < 4; ++i) {
    int nn = ty + i * 8;
    float v = sh[tx][nn];                      // = W[k0+tx][n0+nn]
    size_t o = (size_t)(n0 + nn) * 1024 + k0 + tx;
    _Float16 h = (_Float16)v;
    if (!z) {
      WiT[o] = h;
    } else {
      WhTh[o] = h;
      if (wlo) WhTl[o] = (_Float16)(v - (float)h);
    }
  }
}

// ------------------------------- GEMM core ----------------------------------
// BMt x BNt tile, BKt in {64,128}, 4 waves (2x2).  LDS [rows][BKt/8 slots of
// 8 fp16]; linear slot holds k-group (slot ^ (row&7)): inverse-swizzled
// global source for global_load_lds (dest linear) + same XOR on ds_read.
// K-loop: barrier; stage-DMA(kt); barrier; compute(kt).

template <bool LO, int BMt, int BNt, int BKt>
__device__ __forceinline__ void kloop(
    const _Float16* __restrict__ A, const _Float16* __restrict__ Bh,
    const _Float16* __restrict__ Bl, _Float16* lds, int tid,
    f32x4 (&acc)[BMt / 32][BNt / 32]) {
  constexpr int TA = BMt * BKt, TB = BNt * BKt;
  constexpr int MF = BMt / 32, WC = BNt / 32;
  constexpr int NT = 1024 / BKt;
  constexpr int RPC = 512 / BKt;          // rows per 1KB staging chunk
  constexpr int SLOTS = BKt / 8;          // 16B k-groups per row
  constexpr int AW = TA / 512 / 4;        // A chunks per wave
  constexpr int BW = TB / 512 / 4;        // B chunks per wave
  const int lane = tid & 63, wid = tid >> 6;
  const int srow  = lane / SLOTS;         // row within chunk
  const int sslot = lane % SLOTS;
  const int wrow = (wid >> 1) * (BMt / 2);
  const int wcol = (wid & 1) * (BNt / 2);

  for (int kt = 0; kt < NT; ++kt) {
    const int k0 = kt * BKt;
    __syncthreads();                  // all waves done reading prev tile
#pragma unroll
    for (int i = 0; i < AW; ++i) {
      int c = wid * AW + i;
      int rg = c * RPC + srow;
      gload16(A + (size_t)rg * 1024 + k0 + ((sslot ^ (rg & 7)) << 3),
              lds + c * 512);
    }
#pragma unroll
    for (int i = 0; i < BW; ++i) {
      int c = wid * BW + i;
      int rg = c * RPC + srow;
      size_t go = (size_t)rg * 1024 + k0 + ((sslot ^ (rg & 7)) << 3);
      gload16(Bh + go, lds + TA + c * 512);
      if constexpr (LO) gload16(Bl + go, lds + TA + TB + c * 512);
    }
    __syncthreads();                  // drains vmcnt(0) -> LDS valid

#pragma unroll
    for (int h = 0; h < BKt / 32; ++h) {
      half8 a[MF], bhv[WC], blv[WC];
      const int kg = h * 4 + (lane >> 4);
#pragma unroll
      for (int m = 0; m < MF; ++m) {
        int r = wrow + m * 16 + (lane & 15);
        a[m] = *(const half8*)(lds + r * BKt + ((kg ^ (r & 7)) << 3));
      }
#pragma unroll
      for (int n = 0; n < WC; ++n) {
        int r = wcol + n * 16 + (lane & 15);
        int off = TA + r * BKt + ((kg ^ (r & 7)) << 3);
        bhv[n] = *(const half8*)(lds + off);
        if constexpr (LO) blv[n] = *(const half8*)(lds + TB + off);
      }
#pragma unroll
      for (int m = 0; m < MF; ++m)
#pragma unroll
        for (int n = 0; n < WC; ++n) {
          acc[m][n] = __builtin_amdgcn_mfma_f32_16x16x32_f16(
              a[m], bhv[n], acc[m][n], 0, 0, 0);
          if constexpr (LO)
            acc[m][n] = __builtin_amdgcn_mfma_f32_16x16x32_f16(
                a[m], blv[n], acc[m][n], 0, 0, 0);
        }
    }
  }
}

// ---- MEGA: 1536 blocks.  0..1023: 128x128 1-pass over [g | gh_u] (4096c).
//                          1024..1535: 128x64 2-pass over gh_r (1024c).
// Block order within XCD: column-panel fastest (bx-fast) so co-resident
// blocks share the A row-stripe in L2 and B panels stay resident.
__global__ __launch_bounds__(256, 4) void gemm_mega(
    const _Float16* __restrict__ Xf16, const _Float16* __restrict__ Hf16,
    const _Float16* __restrict__ WiT, const _Float16* __restrict__ WhTh,
    const _Float16* __restrict__ WhTl, _Float16* __restrict__ g16,
    _Float16* __restrict__ ghbuf, float* __restrict__ psum,
    float* __restrict__ psq) {
  __shared__ _Float16 lds[16384];                    // 32 KiB both phases

  const int tid  = threadIdx.x;
  const int lane = tid & 63;
  const int wid  = tid >> 6;
  const int bid  = blockIdx.x;

  if (bid < 1024) {
    // ---- phase 1: 128x128, 1-pass.  XCD owns 4 col-panels; bx fast.
    int xcd   = bid & 7;
    int local = bid >> 3;                            // 0..127
    int bx = xcd * 4 + (local & 3);                  // 0..31
    int by = local >> 2;                             // 0..31
    const int brow = by * 128;
    const int bcol = bx * 128;                       // 0..4095
    const bool is_g = bcol < 3072;
    const int wrow = (wid >> 1) * 64;
    const int wcol = (wid & 1) * 64;

    const _Float16* Ap = (is_g ? Xf16 : Hf16) + (size_t)brow * 1024;
    const _Float16* Bp = is_g ? WiT + (size_t)bcol * 1024
                              : WhTh + (size_t)(bcol - 3072) * 1024;

    f32x4 acc[4][4];
#pragma unroll
    for (int i = 0; i < 4; ++i)
#pragma unroll
      for (int j = 0; j < 4; ++j) acc[i][j] = f32x4{0.f, 0.f, 0.f, 0.f};

    kloop<false, 128, 128, 64>(Ap, Bp, nullptr, lds, tid, acc);

    // D(row,col): col = lane&15, row = (lane>>4)*4 + j
    if (is_g) {                       // g (fp16) + BN column partial sums
      float s[4] = {0.f, 0.f, 0.f, 0.f}, q[4] = {0.f, 0.f, 0.f, 0.f};
#pragma unroll
      for (int m = 0; m < 4; ++m) {
        int row = brow + wrow + m * 16 + (lane >> 4) * 4;
#pragma unroll
        for (int n = 0; n < 4; ++n) {
          int gcol = bcol + wcol + n * 16 + (lane & 15);
#pragma unroll
          for (int j = 0; j < 4; ++j) {
            float v = acc[m][n][j];
            g16[(size_t)(row + j) * 3072 + gcol] = (_Float16)v;
            s[n] += v;
            q[n] += v * v;
          }
        }
      }
#pragma unroll
      for (int n = 0; n < 4; ++n) {
        float sv = s[n], qv = q[n];
        sv += __shfl_xor(sv, 16); sv += __shfl_xor(sv, 32);
        qv += __shfl_xor(qv, 16); qv += __shfl_xor(qv, 32);
        if (lane < 16) {
          int prow = by * 2 + (wid >> 1);            // 64 partial rows
          int pcol = bcol + wcol + n * 16 + lane;
          psum[(size_t)prow * 3072 + pcol] = sv;
          psq [(size_t)prow * 3072 + pcol] = qv;
        }
      }
    } else {                          // raw gh_u (fp16), ghbuf stride 2048
      int gh0 = bcol - 3072;
#pragma unroll
      for (int m = 0; m < 4; ++m) {
        int row = brow + wrow + m * 16 + (lane >> 4) * 4;
#pragma unroll
        for (int n = 0; n < 4; ++n) {
          int gcol = gh0 + wcol + n * 16 + (lane & 15);
#pragma unroll
          for (int j = 0; j < 4; ++j)
            ghbuf[(size_t)(row + j) * 2048 + gcol] = (_Float16)acc[m][n][j];
        }
      }
    }
  } else {
    // ---- phase 2: 128x64, 2-pass (B hi+lo) over gh_r.  XCD: 2 panels, bx fast.
    int b2    = bid - 1024;                          // 0..511
    int xcd   = b2 & 7;
    int local = b2 >> 3;                             // 0..63
    int bx = xcd * 2 + (local & 1);                  // 0..15
    int by = local >> 1;                             // 0..31
    const int brow = by * 128;
    const int bcol = bx * 64;                        // 0..1023 within r
    const int wrow = (wid >> 1) * 64;
    const int wcol = (wid & 1) * 32;

    const _Float16* Ap = Hf16 + (size_t)brow * 1024;
    const _Float16* Bp = WhTh + (size_t)(1024 + bcol) * 1024;
    const _Float16* Bl = WhTl + (size_t)(1024 + bcol) * 1024;

    f32x4 acc[4][2];
#pragma unroll
    for (int i = 0; i < 4; ++i)
#pragma unroll
      for (int j = 0; j < 2; ++j) acc[i][j] = f32x4{0.f, 0.f, 0.f, 0.f};

    kloop<true, 128, 64, 64>(Ap, Bp, Bl, lds, tid, acc);

#pragma unroll
    for (int m = 0; m < 4; ++m) {
      int row = brow + wrow + m * 16 + (lane >> 4) * 4;
#pragma unroll
      for (int n = 0; n < 2; ++n) {
        int gcol = 1024 + bcol + wcol + n * 16 + (lane & 15);   // gh_r cols
#pragma unroll
        for (int j = 0; j < 4; ++j)
          ghbuf[(size_t)(row + j) * 2048 + gcol] = (_Float16)acc[m][n][j];
      }
    }
  }
}

// ---- GEMM3: ch = rx @ wh_c (64x64 tiles, BK=128, 1024 blocks);
//      epilogue computes u (from raw gh_u) and hy.
__global__ __launch_bounds__(256, 4) void gemm_last(
    const _Float16* __restrict__ RXf16, const _Float16* __restrict__ Bc,
    const _Float16* __restrict__ g16, const _Float16* __restrict__ ghbuf,
    const _Float16* __restrict__ Hf16, const float* __restrict__ scale,
    const float* __restrict__ shift, float* __restrict__ out) {
  __shared__ _Float16 lds[64 * 128 + 64 * 128];      // 32 KiB

  const int tid  = threadIdx.x;
  const int lane = tid & 63;
  const int wid  = tid >> 6;

  int bid   = blockIdx.x;                            // 0..1023
  int xcd   = bid & 7;
  int local = bid >> 3;                              // 0..127
  int bx = xcd * 2 + (local & 1);                    // 0..15
  int by = local >> 1;                               // 0..63

  const int brow = by * 64;
  const int bcol = bx * 64;                          // 0..1023
  const int wrow = (wid >> 1) * 32;
  const int wcol = (wid & 1) * 32;

  f32x4 acc[2][2];
#pragma unroll
  for (int i = 0; i < 2; ++i)
#pragma unroll
    for (int j = 0; j < 2; ++j) acc[i][j] = f32x4{0.f, 0.f, 0.f, 0.f};

  kloop<false, 64, 64, 128>(RXf16 + (size_t)brow * 1024,
                            Bc + (size_t)bcol * 1024, nullptr, lds, tid, acc);

#pragma unroll
  for (int m = 0; m < 2; ++m) {
    int row0 = brow + wrow + m * 16 + (lane >> 4) * 4;
#pragma unroll
    for (int n = 0; n < 2; ++n) {
      int lcol = bcol + wcol + n * 16 + (lane & 15);
      float sc_u = scale[lcol],        sf_u = shift[lcol];
      float sc_c = scale[2048 + lcol], sf_c = shift[2048 + lcol];
#pragma unroll
      for (int j = 0; j < 4; ++j) {
        int row = row0 + j;
        float gu = (float)g16[(size_t)row * 3072 + lcol];
        float hu = (float)ghbuf[(size_t)row * 2048 + lcol];
        float u  = sigm(gu * sc_u + sf_u + hu);
        float gc = (float)g16[(size_t)row * 3072 + 2048 + lcol];
        float c  = tanh_sat(gc * sc_c + sf_c + acc[m][n][j]);
        float x  = (float)Hf16[(size_t)row * 1024 + lcol];
        out[(size_t)row * 1024 + lcol] = x + u * (c - x);
      }
    }
  }
}

// --------------------------- BN final ---------------------------------------

__global__ void bn_final(const float* __restrict__ psum, const float* __restrict__ psq,
                         const float* __restrict__ gamma, const float* __restrict__ beta,
                         const float* __restrict__ bias, float* __restrict__ scale,
                         float* __restrict__ shift, int nparts, int Ncols, float invM) {
  int col = blockIdx.x * blockDim.x + threadIdx.x;
  if (col >= Ncols) return;
  float s = 0.f, q = 0.f;
  for (int i = 0; i < nparts; ++i) {
    s += psum[(size_t)i * Ncols + col];
    q += psq [(size_t)i * Ncols + col];
  }
  float m   = s * invM;
  float var = q * invM - m * m;
  float r   = rsqrtf(var + 1e-5f);
  float sc  = r * gamma[col];
  scale[col] = sc;
  shift[col] = beta[col] + bias[col] - m * sc;
}

// --------------------- rx = sigmoid(BN(g_r)+gh_r) * hx ----------------------

__global__ void rx_split(const _Float16* __restrict__ g16,
                         const _Float16* __restrict__ ghbuf,
                         const _Float16* __restrict__ Hf16,
                         const float* __restrict__ scale,
                         const float* __restrict__ shift,
                         _Float16* __restrict__ rx) {
  int idx = blockIdx.x * blockDim.x + threadIdx.x;   // 4096*256
  int row = idx >> 8;
  int cv  = idx & 255;
  half4 gr = ((const half4*)g16)[(size_t)row * 768 + 256 + cv];   // g cols 1024+
  half4 hr = ((const half4*)ghbuf)[(size_t)row * 512 + 256 + cv]; // gh cols 1024+
  half4 xv = ((const half4*)Hf16)[(size_t)row * 256 + cv];
  int col = 1024 + cv * 4;
  f4 sr = *(const f4*)&scale[col];
  f4 fr = *(const f4*)&shift[col];
  half4 o;
#pragma unroll
  for (int j = 0; j < 4; ++j) {
    float r = sigm((float)gr[j] * sr[j] + fr[j] + (float)hr[j]);
    o[j] = (_Float16)(r * (float)xv[j]);
  }
  ((half4*)rx)[(size_t)row * 256 + cv] = o;
}

// ------------------------------ launch ---------------------------------------

extern "C" void kernel_launch(void* const* d_in, const int* in_sizes, int n_in,
                              void* d_out, int out_size, void* d_ws, size_t ws_size,
                              hipStream_t stream) {
  const float* input = (const float*)d_in[0];   // 4096x1024
  const float* hx    = (const float*)d_in[1];   // 4096x1024
  const float* wi    = (const float*)d_in[2];   // 1024x3072
  const float* wh    = (const float*)d_in[3];   // 1024x3072
  const float* bias  = (const float*)d_in[4];   // 3072
  const float* gamma = (const float*)d_in[5];   // 3072
  const float* beta  = (const float*)d_in[6];   // 3072
  float* out = (float*)d_out;

  const int B = 4096, N3 = 3072;

  char* ws = (char*)d_ws;
  _Float16* g16   = (_Float16*)(ws);               // 24 MiB [4096][3072]
  _Float16* ghbuf = (_Float16*)(ws + 25165824);    // 16 MiB [4096][2048] raw
  _Float16* Xf16  = (_Float16*)(ws + 41943040);    // 8 MiB
  _Float16* Hf16  = (_Float16*)(ws + 50331648);    // 8 MiB
  _Float16* RXf16 = (_Float16*)(ws + 58720256);    // 8 MiB
  _Float16* WiT   = (_Float16*)(ws + 67108864);    // 6 MiB
  _Float16* WhTh  = (_Float16*)(ws + 73400320);    // 6 MiB
  _Float16* WhTl  = (_Float16*)(ws + 79691776);    // 6 MiB (r-cols only)
  float*    psum  = (float*)   (ws + 85983232);    // 768 KiB [64][3072]
  float*    psq   = (float*)   (ws + 86769664);    // 768 KiB
  float*    scale = (float*)   (ws + 87556096);    // 12 KiB
  float*    shift = (float*)   (ws + 87568384);    // 12 KiB

  // ---- prep: converts + transposes, one dispatch
  prep_all<<<8192 + 6144, 256, 0, stream>>>(input, hx, wi, wh,
                                            Xf16, Hf16, WiT, WhTh, WhTl);

  // ---- MEGA GEMM: [g | gh_u] 128x128 1-pass + gh_r 128x64 2-pass
  gemm_mega<<<1536, 256, 0, stream>>>(
      Xf16, Hf16, WiT, WhTh, WhTl, g16, ghbuf, psum, psq);

  // ---- BN fold
  bn_final<<<12, 256, 0, stream>>>(psum, psq, gamma, beta, bias,
                                   scale, shift, 64, N3, 1.f / (float)B);

  // ---- rx = sigmoid(BN(g_r) + gh_r) * hx
  rx_split<<<4096, 256, 0, stream>>>(g16, ghbuf, Hf16, scale, shift, RXf16);

  // ---- GEMM3 + fused u/c/hy epilogue (64x64, BK=128, 1024 blocks)
  gemm_last<<<1024, 256, 0, stream>>>(
      RXf16, WhTh + (size_t)2048 * 1024, g16, ghbuf, Hf16, scale, shift, out);
}

// Round 15
// 116.344 us; speedup vs baseline: 1.0651x; 1.0144x over previous
//
#include <hip/hip_runtime.h>
#include <cstdint>

// ---------------------------------------------------------------------------
// GRUCell w/ BatchNorm on input projection.  B=4096, I=H=1024, 3H=3072.
// Reference:  c = tanh(c_bn + (r * hx) @ c_h)  (Python left-assoc * then @).
// fp16 scheme (mfma_f32_16x16x32_f16, fp32 accum):
//   MEGA (one dispatch, 1536 blocks, 32KB LDS both phases):
//     blocks 0..1023 : 128x128 1-pass over [g(3072c) | gh_u(1024c)]
//     blocks 1024..1535: 128x64 2-pass (B hi+lo) over gh_r(1024c)
//   bn_final -> scale/shift;  rx = sigmoid(BN(g_r)+gh_r)*hx  (fp16)
//   GEMM3: ch = rx @ wh_c, 64x64 tiles BK=128, 1024 blocks; epilogue u+hy.
// Lessons: blocks/CU >= 4 beats tile density (r5/r11); BK depth is the safe
// density lever (r12); NO reg round-trip in mega staging (r6/r13).
// Round-15: 2D XCD tiling (phase-1 4col x 2row, phase-2/last 2x4) -- r14's
// col-only XCD map re-fetched A once per XCD (FETCH 78.6MB vs 34 compulsory).
// ---------------------------------------------------------------------------

typedef float    f4    __attribute__((ext_vector_type(4)));
typedef _Float16 half4 __attribute__((ext_vector_type(4)));
typedef _Float16 half8 __attribute__((ext_vector_type(8)));
typedef float    f32x4 __attribute__((ext_vector_type(4)));

__device__ __forceinline__ float sigm(float x) { return 1.f / (1.f + __expf(-x)); }
__device__ __forceinline__ float tanh_sat(float t) {
  return 1.f - 2.f / (__expf(2.f * t) + 1.f);   // saturates correctly for big t
}

// async global->LDS DMA, 16B/lane: LDS dst = wave-uniform base + lane*16
__device__ __forceinline__ void gload16(const _Float16* g, _Float16* l) {
  __builtin_amdgcn_global_load_lds(
      (const __attribute__((address_space(1))) void*)g,
      (__attribute__((address_space(3))) void*)l, 16, 0, 0);
}

// --------------------------- prep (one dispatch) ----------------------------
// bid < 8192: f32->fp16 convert of input+hx (x4 vectorized; 2*1048576 float4s).
// bid >= 8192: 32x32 transpose tiles; z=0 -> wi->WiT; z=1 -> wh->WhTh(+lo r).

__global__ void prep_all(const float* __restrict__ input, const float* __restrict__ hx,
                         const float* __restrict__ wi, const float* __restrict__ wh,
                         _Float16* __restrict__ Xf16, _Float16* __restrict__ Hf16,
                         _Float16* __restrict__ WiT, _Float16* __restrict__ WhTh,
                         _Float16* __restrict__ WhTl) {
  constexpr int N4 = 4096 * 1024 / 4;   // float4s per input array = 1048576
  __shared__ float sh[32][33];
  int bid = blockIdx.x;
  if (bid < 8192) {                     // 8192*256 = 2*N4 threads exactly
    int i = bid * 256 + threadIdx.x;
    const float* s;
    _Float16* d;
    if (i < N4) { s = input; d = Xf16; }
    else        { s = hx;    d = Hf16; i -= N4; }
    f4 v = ((const f4*)s)[i];
    half4 h;
#pragma unroll
    for (int j = 0; j < 4; ++j) h[j] = (_Float16)v[j];
    ((half4*)d)[i] = h;
    return;
  }
  int b2 = bid - 8192;                  // 0..6143: [z][ky 0..31][nx 0..95]
  int z = b2 / 3072; b2 %= 3072;
  int nx = b2 % 96, ky = b2 / 96;
  const float* W = z ? wh : wi;
  int n0 = nx * 32, k0 = ky * 32;
  int tx = threadIdx.x & 31, ty = threadIdx.x >> 5;  // ty 0..7
#pragma unroll
  for (int i = 0; i < 4; ++i) {
    int k = ty + i * 8;
    sh[k][tx] = W[(size_t)(k0 + k) * 3072 + n0 + tx];
  }
  __syncthreads();
  const bool wlo = z && n0 >= 1024 && n0 < 2048;     // r-cols need lo part
#pragma unroll
  for (int i = 0; i < 4; ++i) {
    int nn = ty + i * 8;
    float v = sh[tx][nn];                      // = W[k0+tx][n0+nn]
    size_t o = (size_t)(n0 + nn) * 1024 + k0 + tx;
    _Float16 h = (_Float16)v;
    if (!z) {
      WiT[o] = h;
    } else {
      WhTh[o] = h;
      if (wlo) WhTl[o] = (_Float16)(v - (float)h);
    }
  }
}

// ------------------------------- GEMM core ----------------------------------
// BMt x BNt tile, BKt in {64,128}, 4 waves (2x2).  LDS [rows][BKt/8 slots of
// 8 fp16]; linear slot holds k-group (slot ^ (row&7)): inverse-swizzled
// global source for global_load_lds (dest linear) + same XOR on ds_read.
// K-loop: barrier; stage-DMA(kt); barrier; compute(kt).

template <bool LO, int BMt, int BNt, int BKt>
__device__ __forceinline__ void kloop(
    const _Float16* __restrict__ A, const _Float16* __restrict__ Bh,
    const _Float16* __restrict__ Bl, _Float16* lds, int tid,
    f32x4 (&acc)[BMt / 32][BNt / 32]) {
  constexpr int TA = BMt * BKt, TB = BNt * BKt;
  constexpr int MF = BMt / 32, WC = BNt / 32;
  constexpr int NT = 1024 / BKt;
  constexpr int RPC = 512 / BKt;          // rows per 1KB staging chunk
  constexpr int SLOTS = BKt / 8;          // 16B k-groups per row
  constexpr int AW = TA / 512 / 4;        // A chunks per wave
  constexpr int BW = TB / 512 / 4;        // B chunks per wave
  const int lane = tid & 63, wid = tid >> 6;
  const int srow  = lane / SLOTS;         // row within chunk
  const int sslot = lane % SLOTS;
  const int wrow = (wid >> 1) * (BMt / 2);
  const int wcol = (wid & 1) * (BNt / 2);

  for (int kt = 0; kt < NT; ++kt) {
    const int k0 = kt * BKt;
    __syncthreads();                  // all waves done reading prev tile
#pragma unroll
    for (int i = 0; i < AW; ++i) {
      int c = wid * AW + i;
      int rg = c * RPC + srow;
      gload16(A + (size_t)rg * 1024 + k0 + ((sslot ^ (rg & 7)) << 3),
              lds + c * 512);
    }
#pragma unroll
    for (int i = 0; i < BW; ++i) {
      int c = wid * BW + i;
      int rg = c * RPC + srow;
      size_t go = (size_t)rg * 1024 + k0 + ((sslot ^ (rg & 7)) << 3);
      gload16(Bh + go, lds + TA + c * 512);
      if constexpr (LO) gload16(Bl + go, lds + TA + TB + c * 512);
    }
    __syncthreads();                  // drains vmcnt(0) -> LDS valid

#pragma unroll
    for (int h = 0; h < BKt / 32; ++h) {
      half8 a[MF], bhv[WC], blv[WC];
      const int kg = h * 4 + (lane >> 4);
#pragma unroll
      for (int m = 0; m < MF; ++m) {
        int r = wrow + m * 16 + (lane & 15);
        a[m] = *(const half8*)(lds + r * BKt + ((kg ^ (r & 7)) << 3));
      }
#pragma unroll
      for (int n = 0; n < WC; ++n) {
        int r = wcol + n * 16 + (lane & 15);
        int off = TA + r * BKt + ((kg ^ (r & 7)) << 3);
        bhv[n] = *(const half8*)(lds + off);
        if constexpr (LO) blv[n] = *(const half8*)(lds + TB + off);
      }
#pragma unroll
      for (int m = 0; m < MF; ++m)
#pragma unroll
        for (int n = 0; n < WC; ++n) {
          acc[m][n] = __builtin_amdgcn_mfma_f32_16x16x32_f16(
              a[m], bhv[n], acc[m][n], 0, 0, 0);
          if constexpr (LO)
            acc[m][n] = __builtin_amdgcn_mfma_f32_16x16x32_f16(
                a[m], blv[n], acc[m][n], 0, 0, 0);
        }
    }
  }
}

// ---- MEGA: 1536 blocks.  0..1023: 128x128 1-pass over [g | gh_u] (4096c).
//                          1024..1535: 128x64 2-pass over gh_r (1024c).
// 2D XCD tiling: phase-1 XCD = (colgrp = xcd&3 of 8 panels, rowgrp = xcd>>2
// of 16 stripes); bx fastest within XCD so resident blocks share the A
// stripe and the 8 B panels (2MB) stay L2-resident.  A read by 4 XCDs (was
// 8), B by 2 (was 1) -> predicted FETCH 78.6 -> ~55-60 MB.
__global__ __launch_bounds__(256, 4) void gemm_mega(
    const _Float16* __restrict__ Xf16, const _Float16* __restrict__ Hf16,
    const _Float16* __restrict__ WiT, const _Float16* __restrict__ WhTh,
    const _Float16* __restrict__ WhTl, _Float16* __restrict__ g16,
    _Float16* __restrict__ ghbuf, float* __restrict__ psum,
    float* __restrict__ psq) {
  __shared__ _Float16 lds[16384];                    // 32 KiB both phases

  const int tid  = threadIdx.x;
  const int lane = tid & 63;
  const int wid  = tid >> 6;
  const int bid  = blockIdx.x;

  if (bid < 1024) {
    // ---- phase 1: 128x128, 1-pass.  XCD = 4 colgrp x 2 rowgrp; bx fast.
    int xcd = bid & 7;
    int i   = bid >> 3;                              // 0..127
    int bx  = (xcd & 3) * 8 + (i & 7);               // 0..31
    int by  = (xcd >> 2) * 16 + (i >> 3);            // 0..31
    const int brow = by * 128;
    const int bcol = bx * 128;                       // 0..4095
    const bool is_g = bcol < 3072;
    const int wrow = (wid >> 1) * 64;
    const int wcol = (wid & 1) * 64;

    const _Float16* Ap = (is_g ? Xf16 : Hf16) + (size_t)brow * 1024;
    const _Float16* Bp = is_g ? WiT + (size_t)bcol * 1024
                              : WhTh + (size_t)(bcol - 3072) * 1024;

    f32x4 acc[4][4];
#pragma unroll
    for (int a = 0; a < 4; ++a)
#pragma unroll
      for (int j = 0; j < 4; ++j) acc[a][j] = f32x4{0.f, 0.f, 0.f, 0.f};

    kloop<false, 128, 128, 64>(Ap, Bp, nullptr, lds, tid, acc);

    // D(row,col): col = lane&15, row = (lane>>4)*4 + j
    if (is_g) {                       // g (fp16) + BN column partial sums
      float s[4] = {0.f, 0.f, 0.f, 0.f}, q[4] = {0.f, 0.f, 0.f, 0.f};
#pragma unroll
      for (int m = 0; m < 4; ++m) {
        int row = brow + wrow + m * 16 + (lane >> 4) * 4;
#pragma unroll
        for (int n = 0; n < 4; ++n) {
          int gcol = bcol + wcol + n * 16 + (lane & 15);
#pragma unroll
          for (int j = 0; j < 4; ++j) {
            float v = acc[m][n][j];
            g16[(size_t)(row + j) * 3072 + gcol] = (_Float16)v;
            s[n] += v;
            q[n] += v * v;
          }
        }
      }
#pragma unroll
      for (int n = 0; n < 4; ++n) {
        float sv = s[n], qv = q[n];
        sv += __shfl_xor(sv, 16); sv += __shfl_xor(sv, 32);
        qv += __shfl_xor(qv, 16); qv += __shfl_xor(qv, 32);
        if (lane < 16) {
          int prow = by * 2 + (wid >> 1);            // 64 partial rows
          int pcol = bcol + wcol + n * 16 + lane;
          psum[(size_t)prow * 3072 + pcol] = sv;
          psq [(size_t)prow * 3072 + pcol] = qv;
        }
      }
    } else {                          // raw gh_u (fp16), ghbuf stride 2048
      int gh0 = bcol - 3072;
#pragma unroll
      for (int m = 0; m < 4; ++m) {
        int row = brow + wrow + m * 16 + (lane >> 4) * 4;
#pragma unroll
        for (int n = 0; n < 4; ++n) {
          int gcol = gh0 + wcol + n * 16 + (lane & 15);
#pragma unroll
          for (int j = 0; j < 4; ++j)
            ghbuf[(size_t)(row + j) * 2048 + gcol] = (_Float16)acc[m][n][j];
        }
      }
    }
  } else {
    // ---- phase 2: 128x64, 2-pass (B hi+lo) over gh_r.  XCD = 2 colgrp x
    // 4 rowgrp; bx fast.
    int b2  = bid - 1024;                            // 0..511
    int xcd = b2 & 7;
    int i   = b2 >> 3;                               // 0..63
    int bx  = (xcd & 1) * 8 + (i & 7);               // 0..15
    int by  = (xcd >> 1) * 8 + (i >> 3);             // 0..31
    const int brow = by * 128;
    const int bcol = bx * 64;                        // 0..1023 within r
    const int wrow = (wid >> 1) * 64;
    const int wcol = (wid & 1) * 32;

    const _Float16* Ap = Hf16 + (size_t)brow * 1024;
    const _Float16* Bp = WhTh + (size_t)(1024 + bcol) * 1024;
    const _Float16* Bl = WhTl + (size_t)(1024 + bcol) * 1024;

    f32x4 acc[4][2];
#pragma unroll
    for (int a = 0; a < 4; ++a)
#pragma unroll
      for (int j = 0; j < 2; ++j) acc[a][j] = f32x4{0.f, 0.f, 0.f, 0.f};

    kloop<true, 128, 64, 64>(Ap, Bp, Bl, lds, tid, acc);

#pragma unroll
    for (int m = 0; m < 4; ++m) {
      int row = brow + wrow + m * 16 + (lane >> 4) * 4;
#pragma unroll
      for (int n = 0; n < 2; ++n) {
        int gcol = 1024 + bcol + wcol + n * 16 + (lane & 15);   // gh_r cols
#pragma unroll
        for (int j = 0; j < 4; ++j)
          ghbuf[(size_t)(row + j) * 2048 + gcol] = (_Float16)acc[m][n][j];
      }
    }
  }
}

// ---- GEMM3: ch = rx @ wh_c (64x64 tiles, BK=128, 1024 blocks);
//      epilogue computes u (from raw gh_u) and hy.  XCD = 2 colgrp x 4 rowgrp.
__global__ __launch_bounds__(256, 4) void gemm_last(
    const _Float16* __restrict__ RXf16, const _Float16* __restrict__ Bc,
    const _Float16* __restrict__ g16, const _Float16* __restrict__ ghbuf,
    const _Float16* __restrict__ Hf16, const float* __restrict__ scale,
    const float* __restrict__ shift, float* __restrict__ out) {
  __shared__ _Float16 lds[64 * 128 + 64 * 128];      // 32 KiB

  const int tid  = threadIdx.x;
  const int lane = tid & 63;
  const int wid  = tid >> 6;

  int bid = blockIdx.x;                              // 0..1023
  int xcd = bid & 7;
  int i   = bid >> 3;                                // 0..127
  int bx  = (xcd & 1) * 8 + (i & 7);                 // 0..15
  int by  = (xcd >> 1) * 16 + (i >> 3);              // 0..63

  const int brow = by * 64;
  const int bcol = bx * 64;                          // 0..1023
  const int wrow = (wid >> 1) * 32;
  const int wcol = (wid & 1) * 32;

  f32x4 acc[2][2];
#pragma unroll
  for (int a = 0; a < 2; ++a)
#pragma unroll
    for (int j = 0; j < 2; ++j) acc[a][j] = f32x4{0.f, 0.f, 0.f, 0.f};

  kloop<false, 64, 64, 128>(RXf16 + (size_t)brow * 1024,
                            Bc + (size_t)bcol * 1024, nullptr, lds, tid, acc);

#pragma unroll
  for (int m = 0; m < 2; ++m) {
    int row0 = brow + wrow + m * 16 + (lane >> 4) * 4;
#pragma unroll
    for (int n = 0; n < 2; ++n) {
      int lcol = bcol + wcol + n * 16 + (lane & 15);
      float sc_u = scale[lcol],        sf_u = shift[lcol];
      float sc_c = scale[2048 + lcol], sf_c = shift[2048 + lcol];
#pragma unroll
      for (int j = 0; j < 4; ++j) {
        int row = row0 + j;
        float gu = (float)g16[(size_t)row * 3072 + lcol];
        float hu = (float)ghbuf[(size_t)row * 2048 + lcol];
        float u  = sigm(gu * sc_u + sf_u + hu);
        float gc = (float)g16[(size_t)row * 3072 + 2048 + lcol];
        float c  = tanh_sat(gc * sc_c + sf_c + acc[m][n][j]);
        float x  = (float)Hf16[(size_t)row * 1024 + lcol];
        out[(size_t)row * 1024 + lcol] = x + u * (c - x);
      }
    }
  }
}

// --------------------------- BN final ---------------------------------------

__global__ void bn_final(const float* __restrict__ psum, const float* __restrict__ psq,
                         const float* __restrict__ gamma, const float* __restrict__ beta,
                         const float* __restrict__ bias, float* __restrict__ scale,
                         float* __restrict__ shift, int nparts, int Ncols, float invM) {
  int col = blockIdx.x * blockDim.x + threadIdx.x;
  if (col >= Ncols) return;
  float s = 0.f, q = 0.f;
  for (int i = 0; i < nparts; ++i) {
    s += psum[(size_t)i * Ncols + col];
    q += psq [(size_t)i * Ncols + col];
  }
  float m   = s * invM;
  float var = q * invM - m * m;
  float r   = rsqrtf(var + 1e-5f);
  float sc  = r * gamma[col];
  scale[col] = sc;
  shift[col] = beta[col] + bias[col] - m * sc;
}

// --------------------- rx = sigmoid(BN(g_r)+gh_r) * hx ----------------------

__global__ void rx_split(const _Float16* __restrict__ g16,
                         const _Float16* __restrict__ ghbuf,
                         const _Float16* __restrict__ Hf16,
                         const float* __restrict__ scale,
                         const float* __restrict__ shift,
                         _Float16* __restrict__ rx) {
  int idx = blockIdx.x * blockDim.x + threadIdx.x;   // 4096*256
  int row = idx >> 8;
  int cv  = idx & 255;
  half4 gr = ((const half4*)g16)[(size_t)row * 768 + 256 + cv];   // g cols 1024+
  half4 hr = ((const half4*)ghbuf)[(size_t)row * 512 + 256 + cv]; // gh cols 1024+
  half4 xv = ((const half4*)Hf16)[(size_t)row * 256 + cv];
  int col = 1024 + cv * 4;
  f4 sr = *(const f4*)&scale[col];
  f4 fr = *(const f4*)&shift[col];
  half4 o;
#pragma unroll
  for (int j = 0; j < 4; ++j) {
    float r = sigm((float)gr[j] * sr[j] + fr[j] + (float)hr[j]);
    o[j] = (_Float16)(r * (float)xv[j]);
  }
  ((half4*)rx)[(size_t)row * 256 + cv] = o;
}

// ------------------------------ launch ---------------------------------------

extern "C" void kernel_launch(void* const* d_in, const int* in_sizes, int n_in,
                              void* d_out, int out_size, void* d_ws, size_t ws_size,
                              hipStream_t stream) {
  const float* input = (const float*)d_in[0];   // 4096x1024
  const float* hx    = (const float*)d_in[1];   // 4096x1024
  const float* wi    = (const float*)d_in[2];   // 1024x3072
  const float* wh    = (const float*)d_in[3];   // 1024x3072
  const float* bias  = (const float*)d_in[4];   // 3072
  const float* gamma = (const float*)d_in[5];   // 3072
  const float* beta  = (const float*)d_in[6];   // 3072
  float* out = (float*)d_out;

  const int B = 4096, N3 = 3072;

  char* ws = (char*)d_ws;
  _Float16* g16   = (_Float16*)(ws);               // 24 MiB [4096][3072]
  _Float16* ghbuf = (_Float16*)(ws + 25165824);    // 16 MiB [4096][2048] raw
  _Float16* Xf16  = (_Float16*)(ws + 41943040);    // 8 MiB
  _Float16* Hf16  = (_Float16*)(ws + 50331648);    // 8 MiB
  _Float16* RXf16 = (_Float16*)(ws + 58720256);    // 8 MiB
  _Float16* WiT   = (_Float16*)(ws + 67108864);    // 6 MiB
  _Float16* WhTh  = (_Float16*)(ws + 73400320);    // 6 MiB
  _Float16* WhTl  = (_Float16*)(ws + 79691776);    // 6 MiB (r-cols only)
  float*    psum  = (float*)   (ws + 85983232);    // 768 KiB [64][3072]
  float*    psq   = (float*)   (ws + 86769664);    // 768 KiB
  float*    scale = (float*)   (ws + 87556096);    // 12 KiB
  float*    shift = (float*)   (ws + 87568384);    // 12 KiB

  // ---- prep: converts + transposes, one dispatch
  prep_all<<<8192 + 6144, 256, 0, stream>>>(input, hx, wi, wh,
                                            Xf16, Hf16, WiT, WhTh, WhTl);

  // ---- MEGA GEMM: [g | gh_u] 128x128 1-pass + gh_r 128x64 2-pass
  gemm_mega<<<1536, 256, 0, stream>>>(
      Xf16, Hf16, WiT, WhTh, WhTl, g16, ghbuf, psum, psq);

  // ---- BN fold
  bn_final<<<12, 256, 0, stream>>>(psum, psq, gamma, beta, bias,
                                   scale, shift, 64, N3, 1.f / (float)B);

  // ---- rx = sigmoid(BN(g_r) + gh_r) * hx
  rx_split<<<4096, 256, 0, stream>>>(g16, ghbuf, Hf16, scale, shift, RXf16);

  // ---- GEMM3 + fused u/c/hy epilogue (64x64, BK=128, 1024 blocks)
  gemm_last<<<1024, 256, 0, stream>>>(
      RXf16, WhTh + (size_t)2048 * 1024, g16, ghbuf, Hf16, scale, shift, out);
}